// Round 1
// baseline (704.769 us; speedup 1.0000x reference)
//
#include <hip/hip_runtime.h>
#include <hip/hip_bf16.h>
#include <stdint.h>

#define DEV static __device__ __forceinline__

typedef __attribute__((ext_vector_type(4))) float f32x4;
typedef __attribute__((ext_vector_type(8))) short s16x8;
typedef __attribute__((ext_vector_type(4))) short s16x4;

constexpr int N_TOK = 32768;   // 32^3
constexpr int C_DIM = 1024;
constexpr int C3    = 3072;

DEV float bf2f(short u) { union { float f; uint32_t i; } x; x.i = ((uint32_t)(uint16_t)u) << 16; return x.f; }
DEV short f2bf(float f) { union { float f; uint32_t i; } x; x.f = f; uint32_t r = x.i + 0x7FFFu + ((x.i >> 16) & 1u); return (short)(r >> 16); }

// XOR swizzle for 64-col bf16 LDS tiles: keeps ds_read_b128 frag reads ~conflict-free.
DEV int swz(int row, int col) { return row * 64 + (((col >> 3) ^ (row & 7)) << 3) + (col & 7); }

DEV f32x4 mfma16(s16x8 a, s16x8 b, f32x4 c) {
  return __builtin_amdgcn_mfma_f32_16x16x32_bf16(a, b, c, 0, 0, 0);
}

DEV void gload16(const void* g, void* lds) {
  __builtin_amdgcn_global_load_lds((const __attribute__((address_space(1))) void*)g,
                                   (__attribute__((address_space(3))) void*)lds, 16, 0, 0);
}

DEV float redmax16(float v) {
  v = fmaxf(v, __shfl_xor(v, 1)); v = fmaxf(v, __shfl_xor(v, 2));
  v = fmaxf(v, __shfl_xor(v, 4)); v = fmaxf(v, __shfl_xor(v, 8));
  return v;
}
DEV float redsum16(float v) {
  v += __shfl_xor(v, 1); v += __shfl_xor(v, 2); v += __shfl_xor(v, 4); v += __shfl_xor(v, 8);
  return v;
}

// ---------------- fp32 -> bf16 convert (x) ----------------
__global__ void k_cvt_x(const float* __restrict__ in, short* __restrict__ outb) {
  size_t i = ((size_t)blockIdx.x * 256 + threadIdx.x) * 8;
  float4 a = *(const float4*)(in + i);
  float4 b = *(const float4*)(in + i + 4);
  s16x8 o;
  o[0] = f2bf(a.x); o[1] = f2bf(a.y); o[2] = f2bf(a.z); o[3] = f2bf(a.w);
  o[4] = f2bf(b.x); o[5] = f2bf(b.y); o[6] = f2bf(b.z); o[7] = f2bf(b.w);
  *(s16x8*)(outb + i) = o;
}

// ---------------- transpose + convert (weights -> [ncol][K] bf16) ----------------
__global__ void k_transpose_cvt(const float* __restrict__ in, short* __restrict__ outb,
                                int rin, int cin) {
  __shared__ float t[32][33];
  int tx = threadIdx.x & 31, ty = threadIdx.x >> 5;  // 256 threads: ty 0..7
  int c0 = blockIdx.x * 32, r0 = blockIdx.y * 32;
#pragma unroll
  for (int k = 0; k < 32; k += 8) t[ty + k][tx] = in[(size_t)(r0 + ty + k) * cin + c0 + tx];
  __syncthreads();
#pragma unroll
  for (int k = 0; k < 32; k += 8) outb[(size_t)(c0 + ty + k) * rin + r0 + tx] = f2bf(t[tx][ty + k]);
}

// ---------------- RoPE cos/sin table [32 coords][10 freqs] ----------------
__global__ void k_ctab(float2* __restrict__ ctab) {
  int t = threadIdx.x;
  if (t >= 320) return;
  int c = t / 10, fi = t % 10;
  float freq = powf(10000.0f, -(float)fi / 10.0f);
  float ph = (float)c * freq;
  ctab[t] = make_float2(cosf(ph), sinf(ph));
}

// ---------------- GEMM core: 128x128 tile, BK=32, A[M][K] bf16, Bt[N][K] bf16 ----------------
DEV void gemm_core(const short* __restrict__ A, const short* __restrict__ Bt, int K,
                   int tileM, int tileN, short* As, short* Bs, f32x4 (&acc)[4][4]) {
  const int tid = threadIdx.x;
  const int lane = tid & 63, wid = tid >> 6;
  const int wr = wid >> 1, wc = wid & 1;
  const int g = lane >> 4, r = lane & 15;
#pragma unroll
  for (int m = 0; m < 4; ++m)
#pragma unroll
    for (int n = 0; n < 4; ++n) acc[m][n] = (f32x4)0.0f;
  const int nk = K >> 5;
  for (int k0 = 0; k0 < nk; ++k0) {
    __syncthreads();
#pragma unroll
    for (int i = 0; i < 2; ++i) {
      int seg = i * 256 + tid;
      int row = seg >> 2, off = (seg & 3) * 8;
      gload16(A + (size_t)(tileM + row) * K + (k0 * 32 + off), As + ((size_t)(i * 256 + (tid & ~63))) * 8);
      gload16(Bt + (size_t)(tileN + row) * K + (k0 * 32 + off), Bs + ((size_t)(i * 256 + (tid & ~63))) * 8);
    }
    __syncthreads();  // drains vmcnt (compiler emits s_waitcnt vmcnt(0) before barrier)
    s16x8 af[4], bfr[4];
#pragma unroll
    for (int m = 0; m < 4; ++m) af[m] = *(const s16x8*)(As + (wr * 64 + m * 16 + r) * 32 + g * 8);
#pragma unroll
    for (int n = 0; n < 4; ++n) bfr[n] = *(const s16x8*)(Bs + (wc * 64 + n * 16 + r) * 32 + g * 8);
#pragma unroll
    for (int m = 0; m < 4; ++m)
#pragma unroll
      for (int n = 0; n < 4; ++n) acc[m][n] = mfma16(af[m], bfr[n], acc[m][n]);
  }
}

// ---------------- GEMM1: qkv = x@Wqkv + b, scatter into windowed q/k/v ----------------
__global__ __launch_bounds__(256) void k_gemm_qkv(const short* __restrict__ A, const short* __restrict__ Bt,
                                                  const float* __restrict__ bias,
                                                  short* __restrict__ qw, short* __restrict__ kw,
                                                  short* __restrict__ vw) {
  __shared__ __align__(16) short As[128 * 32];
  __shared__ __align__(16) short Bs[128 * 32];
  const int tileM = blockIdx.y * 128, tileN = blockIdx.x * 128;
  f32x4 acc[4][4];
  gemm_core(A, Bt, C_DIM, tileM, tileN, As, Bs, acc);

  const int tid = threadIdx.x, lane = tid & 63, wid = tid >> 6;
  const int wr = wid >> 1, wc = wid & 1, g = lane >> 4, r = lane & 15;
  const int part = tileN >> 10;                       // uniform per block (128 | 1024)
  short* buf = (part == 0) ? qw : ((part == 1) ? kw : vw);
  const int head = ((tileN + wc * 64) >> 6) & 15;     // uniform per wave
#pragma unroll
  for (int m = 0; m < 4; ++m) {
#pragma unroll
    for (int j = 0; j < 4; ++j) {
      int gr = tileM + wr * 64 + m * 16 + g * 4 + j;  // token id
      int gx = gr >> 10, gy = (gr >> 5) & 31, gz = gr & 31;
      int w = ((gx >> 3) << 4) | ((gy >> 3) << 2) | (gz >> 3);
      int idx = ((gx & 7) << 6) | ((gy & 7) << 3) | (gz & 7);
      size_t base = ((size_t)(w * 16 + head) * 512 + idx) * 64;
#pragma unroll
      for (int n = 0; n < 4; ++n) {
        int d = n * 16 + r;
        float v = acc[m][n][j] + bias[tileN + wc * 64 + d];
        buf[base + d] = f2bf(v);
      }
    }
  }
}

// ---------------- GEMM2: out = h@Wout + b (fp32 out) ----------------
__global__ __launch_bounds__(256) void k_gemm_out(const short* __restrict__ A, const short* __restrict__ Bt,
                                                  const float* __restrict__ bias, float* __restrict__ out) {
  __shared__ __align__(16) short As[128 * 32];
  __shared__ __align__(16) short Bs[128 * 32];
  const int tileM = blockIdx.y * 128, tileN = blockIdx.x * 128;
  f32x4 acc[4][4];
  gemm_core(A, Bt, C_DIM, tileM, tileN, As, Bs, acc);
  const int tid = threadIdx.x, lane = tid & 63, wid = tid >> 6;
  const int wr = wid >> 1, wc = wid & 1, g = lane >> 4, r = lane & 15;
#pragma unroll
  for (int m = 0; m < 4; ++m)
#pragma unroll
    for (int j = 0; j < 4; ++j) {
      int gr = tileM + wr * 64 + m * 16 + g * 4 + j;
#pragma unroll
      for (int n = 0; n < 4; ++n) {
        int gc = tileN + wc * 64 + n * 16 + r;
        out[(size_t)gr * C_DIM + gc] = acc[m][n][j] + bias[gc];
      }
    }
}

// ---------------- in-place RMS-norm + RoPE on windowed q,k ----------------
// One wave handles 4 rows; lane = (row g = lane>>4, 4 d-elems at (lane&15)*4).
__global__ __launch_bounds__(256) void k_normrope(short* __restrict__ qw, short* __restrict__ kw,
                                                  const float* __restrict__ gq, const float* __restrict__ gk,
                                                  const float2* __restrict__ ctab) {
  const int tid = threadIdx.x, lane = tid & 63, wid = tid >> 6;
  const int g = lane >> 4, r = lane & 15;
  uint32_t rid = (uint32_t)blockIdx.x * 16 + wid * 4 + g;
  const int isK = rid >= (1u << 19);
  uint32_t rr = rid & ((1u << 19) - 1);
  short* buf = isK ? kw : qw;
  const float* gamma = isK ? gk : gq;
  uint32_t w = rr >> 13, head = (rr >> 9) & 15, idx = rr & 511;

  size_t off = (size_t)rr * 64 + r * 4;
  s16x4 v4 = *(const s16x4*)(buf + off);
  float v[4];
#pragma unroll
  for (int e = 0; e < 4; ++e) v[e] = bf2f(v4[e]);
  float ss = v[0] * v[0] + v[1] * v[1] + v[2] * v[2] + v[3] * v[3];
  ss = redsum16(ss);
  float norm = fmaxf(sqrtf(ss), 1e-12f);
  // reference: t/norm * gamma * sqrt(D); score scale 1/sqrt(D) folded into q.
  float sc = (isK ? 8.0f : 1.0f) / norm;
  int d0 = r * 4;
#pragma unroll
  for (int e = 0; e < 4; ++e) v[e] *= sc * gamma[head * 64 + d0 + e];

  int cx = ((w >> 4) << 3) + (idx >> 6);
  int cy = (((w >> 2) & 3) << 3) + ((idx >> 3) & 7);
  int cz = ((w & 3) << 3) + (idx & 7);
#pragma unroll
  for (int pp = 0; pp < 2; ++pp) {
    int p = r * 2 + pp;  // rotation pair index 0..31
    float c = 1.0f, s = 0.0f;
    if (p < 30) {
      int axis = (p >= 20) ? 2 : (p >= 10 ? 1 : 0);
      int fi = p - axis * 10;
      int cc = (axis == 0) ? cx : ((axis == 1) ? cy : cz);
      float2 cs = ctab[cc * 10 + fi];
      c = cs.x; s = cs.y;
    }
    float t0 = v[2 * pp], t1 = v[2 * pp + 1];
    v[2 * pp]     = t0 * c - t1 * s;
    v[2 * pp + 1] = t0 * s + t1 * c;
  }
  s16x4 o4;
#pragma unroll
  for (int e = 0; e < 4; ++e) o4[e] = f2bf(v[e]);
  *(s16x4*)(buf + off) = o4;
}

// ---------------- windowed attention: block = (window, head, 64 q-rows) ----------------
__global__ __launch_bounds__(256) void k_attn(const short* __restrict__ qw, const short* __restrict__ kw,
                                              const short* __restrict__ vw, short* __restrict__ hb) {
  __shared__ __align__(16) short Ks[64 * 64];
  __shared__ __align__(16) short Vt[64 * 64];
  __shared__ __align__(16) short Pb[4 * 16 * 64];
  const int b = blockIdx.x;
  const int qb = b & 7, head = (b >> 3) & 15, w = b >> 7;
  const int tid = threadIdx.x, lane = tid & 63, wid = tid >> 6;
  const int g = lane >> 4, r = lane & 15;

  const short* Qp = qw + ((size_t)(w * 16 + head) * 512 + qb * 64 + wid * 16) * 64;
  const short* Kp = kw + (size_t)(w * 16 + head) * 512 * 64;
  const short* Vp = vw + (size_t)(w * 16 + head) * 512 * 64;

  s16x8 qf[2];
  qf[0] = *(const s16x8*)(Qp + r * 64 + g * 8);
  qf[1] = *(const s16x8*)(Qp + r * 64 + 32 + g * 8);

  f32x4 o[4];
#pragma unroll
  for (int nt = 0; nt < 4; ++nt) o[nt] = (f32x4)0.0f;
  float mrow[4] = {-1e30f, -1e30f, -1e30f, -1e30f};
  float lrow[4] = {0.f, 0.f, 0.f, 0.f};

  short* Pw = Pb + wid * 1024;  // per-wave private 16x64 P buffer

  for (int c = 0; c < 8; ++c) {
    __syncthreads();
    // stage K chunk (64 keys x 64 d), swizzled; b128 writes
#pragma unroll
    for (int i = 0; i < 2; ++i) {
      int seg = i * 256 + tid;
      int key = seg >> 3, d0 = (seg & 7) * 8;
      s16x8 kvv = *(const s16x8*)(Kp + (size_t)(c * 64 + key) * 64 + d0);
      *(s16x8*)(Ks + swz(key, d0)) = kvv;
    }
    // stage V^T (row=d, col=key), swizzled; coalesced-ish global reads, 2B LDS writes
#pragma unroll
    for (int i = 0; i < 2; ++i) {
      int dcol = (wid * 2 + i) * 8;
      s16x8 vv = *(const s16x8*)(Vp + (size_t)(c * 64 + lane) * 64 + dcol);
#pragma unroll
      for (int jj = 0; jj < 8; ++jj) Vt[swz(dcol + jj, lane)] = vv[jj];
    }
    __syncthreads();

    // S = Q K^T  (16 q-rows x 64 keys per wave)
    f32x4 s[4];
#pragma unroll
    for (int nt = 0; nt < 4; ++nt) {
      f32x4 a = (f32x4)0.0f;
      s16x8 k0 = *(const s16x8*)(Ks + swz(nt * 16 + r, g * 8));
      s16x8 k1 = *(const s16x8*)(Ks + swz(nt * 16 + r, 32 + g * 8));
      a = mfma16(qf[0], k0, a);
      a = mfma16(qf[1], k1, a);
      s[nt] = a;
    }

    // online softmax update (rows = g*4+j; cols spread over lane&15 x nt)
    float pnew[4][4];
#pragma unroll
    for (int j = 0; j < 4; ++j) {
      float mx = fmaxf(fmaxf(s[0][j], s[1][j]), fmaxf(s[2][j], s[3][j]));
      mx = redmax16(mx);
      float mn = fmaxf(mrow[j], mx);
      float alpha = __expf(mrow[j] - mn);
      mrow[j] = mn;
      float ps = 0.f;
#pragma unroll
      for (int nt = 0; nt < 4; ++nt) {
        float p = __expf(s[nt][j] - mn);
        pnew[nt][j] = p;
        ps += p;
      }
      ps = redsum16(ps);
      lrow[j] = lrow[j] * alpha + ps;
#pragma unroll
      for (int nt = 0; nt < 4; ++nt) o[nt][j] *= alpha;
    }

    // repack P (C/D layout) -> A-frag layout via per-wave LDS bounce
#pragma unroll
    for (int nt = 0; nt < 4; ++nt)
#pragma unroll
      for (int j = 0; j < 4; ++j) Pw[swz(g * 4 + j, nt * 16 + r)] = f2bf(pnew[nt][j]);
    s16x8 pa0 = *(const s16x8*)(Pw + swz(r, g * 8));
    s16x8 pa1 = *(const s16x8*)(Pw + swz(r, 32 + g * 8));

    // O += P V
#pragma unroll
    for (int nt = 0; nt < 4; ++nt) {
      s16x8 v0 = *(const s16x8*)(Vt + swz(nt * 16 + r, g * 8));
      s16x8 v1 = *(const s16x8*)(Vt + swz(nt * 16 + r, 32 + g * 8));
      o[nt] = mfma16(pa0, v0, o[nt]);
      o[nt] = mfma16(pa1, v1, o[nt]);
    }
  }

  // epilogue: divide by l, un-window, store bf16 h
#pragma unroll
  for (int j = 0; j < 4; ++j) {
    int idx = qb * 64 + wid * 16 + g * 4 + j;
    int gxx = ((w >> 4) << 3) + (idx >> 6);
    int gyy = (((w >> 2) & 3) << 3) + ((idx >> 3) & 7);
    int gzz = ((w & 3) << 3) + (idx & 7);
    size_t n = (size_t)gxx * 1024 + gyy * 32 + gzz;
    float inv = 1.0f / lrow[j];
#pragma unroll
    for (int nt = 0; nt < 4; ++nt)
      hb[n * C_DIM + head * 64 + nt * 16 + r] = f2bf(o[nt][j] * inv);
  }
}

extern "C" void kernel_launch(void* const* d_in, const int* in_sizes, int n_in,
                              void* d_out, int out_size, void* d_ws, size_t ws_size,
                              hipStream_t stream) {
  const float* x    = (const float*)d_in[0];
  // d_in[1] = coords (int32) — values are exactly the meshgrid, recomputed in-kernel
  const float* Wqkv = (const float*)d_in[2];
  const float* bqkv = (const float*)d_in[3];
  const float* gq   = (const float*)d_in[4];
  const float* gk   = (const float*)d_in[5];
  const float* Wout = (const float*)d_in[6];
  const float* bout = (const float*)d_in[7];
  float* out = (float*)d_out;

  char* ws = (char*)d_ws;
  size_t o = 0;
  auto take = [&](size_t b) { char* p = ws + o; o += (b + 255) & ~(size_t)255; return p; };
  short* xb    = (short*)take((size_t)N_TOK * C_DIM * 2);  // reused as hb after GEMM1
  short* wqkvT = (short*)take((size_t)C3 * C_DIM * 2);
  short* woutT = (short*)take((size_t)C_DIM * C_DIM * 2);
  float2* ctab = (float2*)take(320 * sizeof(float2));
  short* qw    = (short*)take((size_t)N_TOK * C_DIM * 2);
  short* kw    = (short*)take((size_t)N_TOK * C_DIM * 2);
  short* vw    = (short*)take((size_t)N_TOK * C_DIM * 2);
  short* hb = xb;

  k_cvt_x<<<(N_TOK * C_DIM) / (256 * 8), 256, 0, stream>>>(x, xb);
  k_transpose_cvt<<<dim3(C3 / 32, C_DIM / 32), 256, 0, stream>>>(Wqkv, wqkvT, C_DIM, C3);
  k_transpose_cvt<<<dim3(C_DIM / 32, C_DIM / 32), 256, 0, stream>>>(Wout, woutT, C_DIM, C_DIM);
  k_ctab<<<1, 320, 0, stream>>>(ctab);
  k_gemm_qkv<<<dim3(C3 / 128, N_TOK / 128), 256, 0, stream>>>(xb, wqkvT, bqkv, qw, kw, vw);
  k_normrope<<<65536, 256, 0, stream>>>(qw, kw, gq, gk, ctab);
  k_attn<<<8192, 256, 0, stream>>>(qw, kw, vw, hb);
  k_gemm_out<<<dim3(C_DIM / 128, N_TOK / 128), 256, 0, stream>>>(hb, woutT, bout, out);
}

// Round 2
// 643.182 us; speedup vs baseline: 1.0958x; 1.0958x over previous
//
#include <hip/hip_runtime.h>
#include <hip/hip_bf16.h>
#include <stdint.h>

#define DEV static __device__ __forceinline__

typedef __attribute__((ext_vector_type(4))) float f32x4;
typedef __attribute__((ext_vector_type(8))) short s16x8;
typedef __attribute__((ext_vector_type(4))) short s16x4;

constexpr int N_TOK = 32768;   // 32^3
constexpr int C_DIM = 1024;
constexpr int C3    = 3072;
constexpr int GK    = 1024;    // K for both GEMMs

DEV float bf2f(short u) { union { float f; uint32_t i; } x; x.i = ((uint32_t)(uint16_t)u) << 16; return x.f; }
DEV short f2bf(float f) { union { float f; uint32_t i; } x; x.f = f; uint32_t r = x.i + 0x7FFFu + ((x.i >> 16) & 1u); return (short)(r >> 16); }

// XOR swizzle for 64-col bf16 LDS tiles (attention kernel).
DEV int swz_at(int row, int col) { return row * 64 + (((col >> 3) ^ (row & 7)) << 3) + (col & 7); }

DEV f32x4 mfma16(s16x8 a, s16x8 b, f32x4 c) {
  return __builtin_amdgcn_mfma_f32_16x16x32_bf16(a, b, c, 0, 0, 0);
}

DEV void gload16(const void* g, void* lds) {
  __builtin_amdgcn_global_load_lds((const __attribute__((address_space(1))) void*)g,
                                   (__attribute__((address_space(3))) void*)lds, 16, 0, 0);
}

DEV float redmax16(float v) {
  v = fmaxf(v, __shfl_xor(v, 1)); v = fmaxf(v, __shfl_xor(v, 2));
  v = fmaxf(v, __shfl_xor(v, 4)); v = fmaxf(v, __shfl_xor(v, 8));
  return v;
}
DEV float redsum16(float v) {
  v += __shfl_xor(v, 1); v += __shfl_xor(v, 2); v += __shfl_xor(v, 4); v += __shfl_xor(v, 8);
  return v;
}

// ---------------- fp32 -> bf16 convert (x) ----------------
__global__ void k_cvt_x(const float* __restrict__ in, short* __restrict__ outb) {
  size_t i = ((size_t)blockIdx.x * 256 + threadIdx.x) * 8;
  float4 a = *(const float4*)(in + i);
  float4 b = *(const float4*)(in + i + 4);
  s16x8 o;
  o[0] = f2bf(a.x); o[1] = f2bf(a.y); o[2] = f2bf(a.z); o[3] = f2bf(a.w);
  o[4] = f2bf(b.x); o[5] = f2bf(b.y); o[6] = f2bf(b.z); o[7] = f2bf(b.w);
  *(s16x8*)(outb + i) = o;
}

// ---------------- transpose + convert (weights -> [ncol][K] bf16) ----------------
__global__ void k_transpose_cvt(const float* __restrict__ in, short* __restrict__ outb,
                                int rin, int cin) {
  __shared__ float t[32][33];
  int tx = threadIdx.x & 31, ty = threadIdx.x >> 5;
  int c0 = blockIdx.x * 32, r0 = blockIdx.y * 32;
#pragma unroll
  for (int k = 0; k < 32; k += 8) t[ty + k][tx] = in[(size_t)(r0 + ty + k) * cin + c0 + tx];
  __syncthreads();
#pragma unroll
  for (int k = 0; k < 32; k += 8) outb[(size_t)(c0 + ty + k) * rin + r0 + tx] = f2bf(t[tx][ty + k]);
}

// ---------------- RoPE cos/sin table [32 coords][10 freqs] ----------------
__global__ void k_ctab(float2* __restrict__ ctab) {
  int t = threadIdx.x;
  if (t >= 320) return;
  int c = t / 10, fi = t % 10;
  float freq = powf(10000.0f, -(float)fi / 10.0f);
  float ph = (float)c * freq;
  ctab[t] = make_float2(cosf(ph), sinf(ph));
}

// ================= 256x256 8-phase GEMM (T2+T3+T4+T5) =================
// 512 threads = 8 waves (2 M x 4 N). BK=64. LDS: 2 bufs x (A 256x64 | B 256x64).
// LDS chunk layout: slot(row, c) = row*8 + (c ^ (row&7)); linear global_load_lds
// dest + inverse-swizzled per-lane global source; ds_read applies same XOR.

#define SB() __builtin_amdgcn_sched_barrier(0)
#define WAIT_VM(N) do { asm volatile("s_waitcnt vmcnt(" #N ")" ::: "memory"); SB(); } while (0)
DEV void bar_top() { SB(); __builtin_amdgcn_s_barrier(); asm volatile("s_waitcnt lgkmcnt(0)" ::: "memory"); SB(); }
DEV void bar_end() { SB(); __builtin_amdgcn_s_barrier(); SB(); }

#define READ_A(b, mh) do { _Pragma("unroll") for (int mi_ = 0; mi_ < 4; ++mi_) \
  _Pragma("unroll") for (int kh_ = 0; kh_ < 2; ++kh_) af[mi_ * 2 + kh_] = LDA(b, (mh) * 4 + mi_, kh_); } while (0)
#define READ_B(b, nh, bfx) do { _Pragma("unroll") for (int ni_ = 0; ni_ < 2; ++ni_) \
  _Pragma("unroll") for (int kh_ = 0; kh_ < 2; ++kh_) (bfx)[ni_ * 2 + kh_] = LDB(b, (nh) * 2 + ni_, kh_); } while (0)
#define MFMAQ(mh, nh, bfx) do { __builtin_amdgcn_s_setprio(1); \
  _Pragma("unroll") for (int mi_ = 0; mi_ < 4; ++mi_) \
  _Pragma("unroll") for (int kh_ = 0; kh_ < 2; ++kh_) \
  _Pragma("unroll") for (int ni_ = 0; ni_ < 2; ++ni_) \
    acc[(mh) * 4 + mi_][(nh) * 2 + ni_] = mfma16(af[mi_ * 2 + kh_], (bfx)[ni_ * 2 + kh_], acc[(mh) * 4 + mi_][(nh) * 2 + ni_]); \
  __builtin_amdgcn_s_setprio(0); } while (0)

DEV void gemm256_core(const short* __restrict__ A, const short* __restrict__ Bt,
                      int tileM, int tileN, short* lds, f32x4 (&acc)[8][4]) {
  const int tid = threadIdx.x;
  const int lane = tid & 63, wid = tid >> 6;
  const int wr = wid >> 2, wc = wid & 3;
  const int g = lane >> 4, r = lane & 15;

#pragma unroll
  for (int mi = 0; mi < 8; ++mi)
#pragma unroll
    for (int ni = 0; ni < 4; ++ni) acc[mi][ni] = (f32x4)0.0f;

  const short* Ag = A + (size_t)tileM * GK;
  const short* Bg = Bt + (size_t)tileN * GK;
  const int ldsA = wr * 8192;                 // this wave's A-half region (within buf)
  const int ldsB = 16384 + (wc >> 1) * 8192;  // this wave's B-half region
  const int brow = (wc & 1) * 64;

  auto stageA = [&](int b, int h, int kt) {
    const short* gb = Ag + (size_t)(h * 128) * GK + kt * 64;
    short* db = lds + b * 32768 + h * 8192 + (tid & 448) * 8;  // wave-uniform dest base
#pragma unroll
    for (int i = 0; i < 2; ++i) {
      int s = i * 512 + tid;
      int row = s >> 3;
      int c = (s & 7) ^ (row & 7);
      gload16(gb + (size_t)row * GK + c * 8, db + i * 4096);
    }
  };
  auto stageB = [&](int b, int h, int kt) {
    const short* gb = Bg + (size_t)(h * 128) * GK + kt * 64;
    short* db = lds + b * 32768 + 16384 + h * 8192 + (tid & 448) * 8;
#pragma unroll
    for (int i = 0; i < 2; ++i) {
      int s = i * 512 + tid;
      int row = s >> 3;
      int c = (s & 7) ^ (row & 7);
      gload16(gb + (size_t)row * GK + c * 8, db + i * 4096);
    }
  };
  auto LDA = [&](int b, int mi, int kh) -> s16x8 {
    int row = mi * 16 + r;
    int c = (kh * 4 + g) ^ (r & 7);
    return *(const s16x8*)(lds + b * 32768 + ldsA + row * 64 + c * 8);
  };
  auto LDB = [&](int b, int ni, int kh) -> s16x8 {
    int row = brow + ni * 16 + r;
    int c = (kh * 4 + g) ^ (r & 7);
    return *(const s16x8*)(lds + b * 32768 + ldsB + row * 64 + c * 8);
  };

  s16x8 af[8], bf0[4], bf1[4];

  // Prologue: K-tile 0 fully -> buf0; K-tile 1 B-halves -> buf1. (12 loads issued)
  stageA(0, 0, 0); stageA(0, 1, 0); stageB(0, 0, 0); stageB(0, 1, 0);
  stageB(1, 0, 1); stageB(1, 1, 1);
  WAIT_VM(4);                      // K-tile 0 landed; B(K1) (4 loads) in flight
  __builtin_amdgcn_s_barrier();

#pragma unroll 1
  for (int t = 0; t < 16; t += 2) {
    const bool s2 = (t + 2 < 16), s3 = (t + 3 < 16);
    // p1: compute (mh0,nh0) of K-tile t (buf0); stage A(t+1)h0 -> buf1
    READ_A(0, 0); READ_B(0, 0, bf0);
    stageA(1, 0, t + 1);
    bar_top(); MFMAQ(0, 0, bf0); bar_end();
    // p2
    READ_B(0, 1, bf1);
    stageA(1, 1, t + 1);
    bar_top(); MFMAQ(0, 1, bf1); bar_end();
    // p3  (buf0 B free after p2 -> stage B(t+2))
    READ_A(0, 1);
    if (s2) stageB(0, 0, t + 2);
    bar_top(); MFMAQ(1, 0, bf0); bar_end();
    // p4  (vmcnt: ensure K-tile t+1 fully landed; 4 = B(t+2) loads in flight)
    if (s2) stageB(0, 1, t + 2);
    bar_top(); MFMAQ(1, 1, bf1);
    if (s2) { WAIT_VM(4); } else { WAIT_VM(0); }
    bar_end();
    // p5: K-tile t+1 (buf1); buf0 A free after p3 -> stage A(t+2)
    READ_A(1, 0); READ_B(1, 0, bf0);
    if (s2) stageA(0, 0, t + 2);
    bar_top(); MFMAQ(0, 0, bf0); bar_end();
    // p6
    READ_B(1, 1, bf1);
    if (s2) stageA(0, 1, t + 2);
    bar_top(); MFMAQ(0, 1, bf1); bar_end();
    // p7  (buf1 B free after p6 -> stage B(t+3))
    READ_A(1, 1);
    if (s3) stageB(1, 0, t + 3);
    bar_top(); MFMAQ(1, 0, bf0); bar_end();
    // p8  (vmcnt: ensure K-tile t+2 landed; 4 = B(t+3) loads in flight)
    if (s3) stageB(1, 1, t + 3);
    bar_top(); MFMAQ(1, 1, bf1);
    WAIT_VM(4);
    bar_end();
  }
}

// ---------------- GEMM1: qkv = x@Wqkv + b, scatter into windowed q/k/v ----------------
__global__ __launch_bounds__(512, 2) void k_gemm_qkv(const short* __restrict__ A, const short* __restrict__ Bt,
                                                     const float* __restrict__ bias,
                                                     short* __restrict__ qw, short* __restrict__ kw,
                                                     short* __restrict__ vw) {
  __shared__ __align__(16) short lds[65536];
  const int nwg = gridDim.x, q8 = nwg >> 3, bid = blockIdx.x;
  const int sb = (bid & 7) * q8 + (bid >> 3);          // bijective XCD swizzle (nwg%8==0)
  const int bx = sb % 12, by = sb / 12;
  const int tileM = by * 256, tileN = bx * 256;
  f32x4 acc[8][4];
  gemm256_core(A, Bt, tileM, tileN, lds, acc);

  const int tid = threadIdx.x, lane = tid & 63, wid = tid >> 6;
  const int wr = wid >> 2, wc = wid & 3, g = lane >> 4, r = lane & 15;
  const int colbase = tileN + wc * 64;
  const int part = colbase >> 10;                      // wave-uniform
  short* buf = (part == 0) ? qw : ((part == 1) ? kw : vw);
  const int head = (colbase >> 6) & 15;                // wave-uniform
#pragma unroll
  for (int mi = 0; mi < 8; ++mi) {
#pragma unroll
    for (int j = 0; j < 4; ++j) {
      int gr = tileM + wr * 128 + mi * 16 + g * 4 + j;  // token id
      int gx = gr >> 10, gy = (gr >> 5) & 31, gz = gr & 31;
      int w = ((gx >> 3) << 4) | ((gy >> 3) << 2) | (gz >> 3);
      int idx = ((gx & 7) << 6) | ((gy & 7) << 3) | (gz & 7);
      size_t base = ((size_t)(w * 16 + head) * 512 + idx) * 64;
#pragma unroll
      for (int ni = 0; ni < 4; ++ni) {
        int d = ni * 16 + r;
        buf[base + d] = f2bf(acc[mi][ni][j] + bias[colbase + d]);
      }
    }
  }
}

// ---------------- GEMM2: out = h@Wout + b (fp32 out) ----------------
__global__ __launch_bounds__(512, 2) void k_gemm_out(const short* __restrict__ A, const short* __restrict__ Bt,
                                                     const float* __restrict__ bias, float* __restrict__ out) {
  __shared__ __align__(16) short lds[65536];
  const int nwg = gridDim.x, q8 = nwg >> 3, bid = blockIdx.x;
  const int sb = (bid & 7) * q8 + (bid >> 3);
  const int bx = sb & 3, by = sb >> 2;
  const int tileM = by * 256, tileN = bx * 256;
  f32x4 acc[8][4];
  gemm256_core(A, Bt, tileM, tileN, lds, acc);

  const int tid = threadIdx.x, lane = tid & 63, wid = tid >> 6;
  const int wr = wid >> 2, wc = wid & 3, g = lane >> 4, r = lane & 15;
#pragma unroll
  for (int mi = 0; mi < 8; ++mi)
#pragma unroll
    for (int j = 0; j < 4; ++j) {
      int gr = tileM + wr * 128 + mi * 16 + g * 4 + j;
#pragma unroll
      for (int ni = 0; ni < 4; ++ni) {
        int gc = tileN + wc * 64 + ni * 16 + r;
        out[(size_t)gr * C_DIM + gc] = acc[mi][ni][j] + bias[gc];
      }
    }
}

// ---------------- in-place RMS-norm + RoPE on windowed q,k ----------------
__global__ __launch_bounds__(256) void k_normrope(short* __restrict__ qw, short* __restrict__ kw,
                                                  const float* __restrict__ gq, const float* __restrict__ gk,
                                                  const float2* __restrict__ ctab) {
  const int tid = threadIdx.x, lane = tid & 63, wid = tid >> 6;
  const int g = lane >> 4, r = lane & 15;
  uint32_t rid = (uint32_t)blockIdx.x * 16 + wid * 4 + g;
  const int isK = rid >= (1u << 19);
  uint32_t rr = rid & ((1u << 19) - 1);
  short* buf = isK ? kw : qw;
  const float* gamma = isK ? gk : gq;
  uint32_t w = rr >> 13, head = (rr >> 9) & 15, idx = rr & 511;

  size_t off = (size_t)rr * 64 + r * 4;
  s16x4 v4 = *(const s16x4*)(buf + off);
  float v[4];
#pragma unroll
  for (int e = 0; e < 4; ++e) v[e] = bf2f(v4[e]);
  float ss = v[0] * v[0] + v[1] * v[1] + v[2] * v[2] + v[3] * v[3];
  ss = redsum16(ss);
  float norm = fmaxf(sqrtf(ss), 1e-12f);
  float sc = (isK ? 8.0f : 1.0f) / norm;   // *sqrt(D) and score-scale folded
  int d0 = r * 4;
#pragma unroll
  for (int e = 0; e < 4; ++e) v[e] *= sc * gamma[head * 64 + d0 + e];

  int cx = ((w >> 4) << 3) + (idx >> 6);
  int cy = (((w >> 2) & 3) << 3) + ((idx >> 3) & 7);
  int cz = ((w & 3) << 3) + (idx & 7);
#pragma unroll
  for (int pp = 0; pp < 2; ++pp) {
    int p = r * 2 + pp;
    float c = 1.0f, s = 0.0f;
    if (p < 30) {
      int axis = (p >= 20) ? 2 : (p >= 10 ? 1 : 0);
      int fi = p - axis * 10;
      int cc = (axis == 0) ? cx : ((axis == 1) ? cy : cz);
      float2 cs = ctab[cc * 10 + fi];
      c = cs.x; s = cs.y;
    }
    float t0 = v[2 * pp], t1 = v[2 * pp + 1];
    v[2 * pp]     = t0 * c - t1 * s;
    v[2 * pp + 1] = t0 * s + t1 * c;
  }
  s16x4 o4;
#pragma unroll
  for (int e = 0; e < 4; ++e) o4[e] = f2bf(v[e]);
  *(s16x4*)(buf + off) = o4;
}

// ---------------- windowed attention: block = (window, head, 64 q-rows) ----------------
__global__ __launch_bounds__(256) void k_attn(const short* __restrict__ qw, const short* __restrict__ kw,
                                              const short* __restrict__ vw, short* __restrict__ hb) {
  __shared__ __align__(16) short Ks[64 * 64];
  __shared__ __align__(16) short Vt[64 * 64];
  __shared__ __align__(16) short Pb[4 * 16 * 64];
  const int b = blockIdx.x;
  const int qb = b & 7, head = (b >> 3) & 15, w = b >> 7;
  const int tid = threadIdx.x, lane = tid & 63, wid = tid >> 6;
  const int g = lane >> 4, r = lane & 15;

  const short* Qp = qw + ((size_t)(w * 16 + head) * 512 + qb * 64 + wid * 16) * 64;
  const short* Kp = kw + (size_t)(w * 16 + head) * 512 * 64;
  const short* Vp = vw + (size_t)(w * 16 + head) * 512 * 64;

  s16x8 qf[2];
  qf[0] = *(const s16x8*)(Qp + r * 64 + g * 8);
  qf[1] = *(const s16x8*)(Qp + r * 64 + 32 + g * 8);

  f32x4 o[4];
#pragma unroll
  for (int nt = 0; nt < 4; ++nt) o[nt] = (f32x4)0.0f;
  float mrow[4] = {-1e30f, -1e30f, -1e30f, -1e30f};
  float lrow[4] = {0.f, 0.f, 0.f, 0.f};

  short* Pw = Pb + wid * 1024;

  for (int c = 0; c < 8; ++c) {
    __syncthreads();
#pragma unroll
    for (int i = 0; i < 2; ++i) {
      int seg = i * 256 + tid;
      int key = seg >> 3, d0 = (seg & 7) * 8;
      s16x8 kvv = *(const s16x8*)(Kp + (size_t)(c * 64 + key) * 64 + d0);
      *(s16x8*)(Ks + swz_at(key, d0)) = kvv;
    }
#pragma unroll
    for (int i = 0; i < 2; ++i) {
      int dcol = (wid * 2 + i) * 8;
      s16x8 vv = *(const s16x8*)(Vp + (size_t)(c * 64 + lane) * 64 + dcol);
#pragma unroll
      for (int jj = 0; jj < 8; ++jj) Vt[swz_at(dcol + jj, lane)] = vv[jj];
    }
    __syncthreads();

    f32x4 s[4];
#pragma unroll
    for (int nt = 0; nt < 4; ++nt) {
      f32x4 a = (f32x4)0.0f;
      s16x8 k0 = *(const s16x8*)(Ks + swz_at(nt * 16 + r, g * 8));
      s16x8 k1 = *(const s16x8*)(Ks + swz_at(nt * 16 + r, 32 + g * 8));
      a = mfma16(qf[0], k0, a);
      a = mfma16(qf[1], k1, a);
      s[nt] = a;
    }

    float pnew[4][4];
#pragma unroll
    for (int j = 0; j < 4; ++j) {
      float mx = fmaxf(fmaxf(s[0][j], s[1][j]), fmaxf(s[2][j], s[3][j]));
      mx = redmax16(mx);
      float mn = fmaxf(mrow[j], mx);
      float alpha = __expf(mrow[j] - mn);
      mrow[j] = mn;
      float ps = 0.f;
#pragma unroll
      for (int nt = 0; nt < 4; ++nt) {
        float p = __expf(s[nt][j] - mn);
        pnew[nt][j] = p;
        ps += p;
      }
      ps = redsum16(ps);
      lrow[j] = lrow[j] * alpha + ps;
#pragma unroll
      for (int nt = 0; nt < 4; ++nt) o[nt][j] *= alpha;
    }

#pragma unroll
    for (int nt = 0; nt < 4; ++nt)
#pragma unroll
      for (int j = 0; j < 4; ++j) Pw[swz_at(g * 4 + j, nt * 16 + r)] = f2bf(pnew[nt][j]);
    s16x8 pa0 = *(const s16x8*)(Pw + swz_at(r, g * 8));
    s16x8 pa1 = *(const s16x8*)(Pw + swz_at(r, 32 + g * 8));

#pragma unroll
    for (int nt = 0; nt < 4; ++nt) {
      s16x8 v0 = *(const s16x8*)(Vt + swz_at(nt * 16 + r, g * 8));
      s16x8 v1 = *(const s16x8*)(Vt + swz_at(nt * 16 + r, 32 + g * 8));
      o[nt] = mfma16(pa0, v0, o[nt]);
      o[nt] = mfma16(pa1, v1, o[nt]);
    }
  }

#pragma unroll
  for (int j = 0; j < 4; ++j) {
    int idx = qb * 64 + wid * 16 + g * 4 + j;
    int gxx = ((w >> 4) << 3) + (idx >> 6);
    int gyy = (((w >> 2) & 3) << 3) + ((idx >> 3) & 7);
    int gzz = ((w & 3) << 3) + (idx & 7);
    size_t n = (size_t)gxx * 1024 + gyy * 32 + gzz;
    float inv = 1.0f / lrow[j];
#pragma unroll
    for (int nt = 0; nt < 4; ++nt)
      hb[n * C_DIM + head * 64 + nt * 16 + r] = f2bf(o[nt][j] * inv);
  }
}

extern "C" void kernel_launch(void* const* d_in, const int* in_sizes, int n_in,
                              void* d_out, int out_size, void* d_ws, size_t ws_size,
                              hipStream_t stream) {
  const float* x    = (const float*)d_in[0];
  const float* Wqkv = (const float*)d_in[2];
  const float* bqkv = (const float*)d_in[3];
  const float* gq   = (const float*)d_in[4];
  const float* gk   = (const float*)d_in[5];
  const float* Wout = (const float*)d_in[6];
  const float* bout = (const float*)d_in[7];
  float* out = (float*)d_out;

  char* ws = (char*)d_ws;
  size_t o = 0;
  auto take = [&](size_t b) { char* p = ws + o; o += (b + 255) & ~(size_t)255; return p; };
  short* xb    = (short*)take((size_t)N_TOK * C_DIM * 2);  // reused as hb after GEMM1
  short* wqkvT = (short*)take((size_t)C3 * C_DIM * 2);
  short* woutT = (short*)take((size_t)C_DIM * C_DIM * 2);
  float2* ctab = (float2*)take(320 * sizeof(float2));
  short* qw    = (short*)take((size_t)N_TOK * C_DIM * 2);
  short* kw    = (short*)take((size_t)N_TOK * C_DIM * 2);
  short* vw    = (short*)take((size_t)N_TOK * C_DIM * 2);
  short* hb = xb;

  k_cvt_x<<<(N_TOK * C_DIM) / (256 * 8), 256, 0, stream>>>(x, xb);
  k_transpose_cvt<<<dim3(C3 / 32, C_DIM / 32), 256, 0, stream>>>(Wqkv, wqkvT, C_DIM, C3);
  k_transpose_cvt<<<dim3(C_DIM / 32, C_DIM / 32), 256, 0, stream>>>(Wout, woutT, C_DIM, C_DIM);
  k_ctab<<<1, 320, 0, stream>>>(ctab);
  k_gemm_qkv<<<(C3 / 256) * (N_TOK / 256), 512, 0, stream>>>(xb, wqkvT, bqkv, qw, kw, vw);
  k_normrope<<<65536, 256, 0, stream>>>(qw, kw, gq, gk, ctab);
  k_attn<<<8192, 256, 0, stream>>>(qw, kw, vw, hb);
  k_gemm_out<<<(C_DIM / 256) * (N_TOK / 256), 512, 0, stream>>>(hb, woutT, bout, out);
}

// Round 5
// 558.666 us; speedup vs baseline: 1.2615x; 1.1513x over previous
//
#include <hip/hip_runtime.h>
#include <hip/hip_bf16.h>
#include <stdint.h>

#define DEV static __device__ __forceinline__

typedef __attribute__((ext_vector_type(4))) float f32x4;
typedef __attribute__((ext_vector_type(8))) short s16x8;
typedef __attribute__((ext_vector_type(4))) short s16x4;

constexpr int N_TOK = 32768;   // 32^3
constexpr int C_DIM = 1024;
constexpr int C3    = 3072;
constexpr int GK    = 1024;    // K for both GEMMs

DEV float bf2f(short u) { union { float f; uint32_t i; } x; x.i = ((uint32_t)(uint16_t)u) << 16; return x.f; }
DEV short f2bf(float f) { union { float f; uint32_t i; } x; x.f = f; uint32_t r = x.i + 0x7FFFu + ((x.i >> 16) & 1u); return (short)(r >> 16); }

DEV f32x4 mfma16(s16x8 a, s16x8 b, f32x4 c) {
  return __builtin_amdgcn_mfma_f32_16x16x32_bf16(a, b, c, 0, 0, 0);
}

DEV void gload16(const void* g, void* lds) {
  __builtin_amdgcn_global_load_lds((const __attribute__((address_space(1))) void*)g,
                                   (__attribute__((address_space(3))) void*)lds, 16, 0, 0);
}

#define SB() __builtin_amdgcn_sched_barrier(0)
#define WAIT_VM(N) do { asm volatile("s_waitcnt vmcnt(" #N ")" ::: "memory"); SB(); } while (0)
DEV void bar_top() { SB(); __builtin_amdgcn_s_barrier(); asm volatile("s_waitcnt lgkmcnt(0)" ::: "memory"); SB(); }
DEV void bar_end() { SB(); __builtin_amdgcn_s_barrier(); SB(); }

DEV float redsum16(float v) {
  v += __shfl_xor(v, 1); v += __shfl_xor(v, 2); v += __shfl_xor(v, 4); v += __shfl_xor(v, 8);
  return v;
}

// ---------------- fp32 -> bf16 convert (x) ----------------
__global__ void k_cvt_x(const float* __restrict__ in, short* __restrict__ outb) {
  size_t i = ((size_t)blockIdx.x * 256 + threadIdx.x) * 8;
  float4 a = *(const float4*)(in + i);
  float4 b = *(const float4*)(in + i + 4);
  s16x8 o;
  o[0] = f2bf(a.x); o[1] = f2bf(a.y); o[2] = f2bf(a.z); o[3] = f2bf(a.w);
  o[4] = f2bf(b.x); o[5] = f2bf(b.y); o[6] = f2bf(b.z); o[7] = f2bf(b.w);
  *(s16x8*)(outb + i) = o;
}

// ---------------- transpose + convert (weights -> [ncol][K] bf16) ----------------
__global__ void k_transpose_cvt(const float* __restrict__ in, short* __restrict__ outb,
                                int rin, int cin) {
  __shared__ float t[32][33];
  int tx = threadIdx.x & 31, ty = threadIdx.x >> 5;
  int c0 = blockIdx.x * 32, r0 = blockIdx.y * 32;
#pragma unroll
  for (int k = 0; k < 32; k += 8) t[ty + k][tx] = in[(size_t)(r0 + ty + k) * cin + c0 + tx];
  __syncthreads();
#pragma unroll
  for (int k = 0; k < 32; k += 8) outb[(size_t)(c0 + ty + k) * rin + r0 + tx] = f2bf(t[tx][ty + k]);
}

// ---------------- RoPE cos/sin table [32 coords][10 freqs] ----------------
__global__ void k_ctab(float2* __restrict__ ctab) {
  int t = threadIdx.x;
  if (t >= 320) return;
  int c = t / 10, fi = t % 10;
  float freq = powf(10000.0f, -(float)fi / 10.0f);
  float ph = (float)c * freq;
  ctab[t] = make_float2(cosf(ph), sinf(ph));
}

// ================= 256x256 8-phase GEMM (T2+T3+T4+T5) =================
#define READ_A(b, mh) do { _Pragma("unroll") for (int mi_ = 0; mi_ < 4; ++mi_) \
  _Pragma("unroll") for (int kh_ = 0; kh_ < 2; ++kh_) af[mi_ * 2 + kh_] = LDA(b, (mh) * 4 + mi_, kh_); } while (0)
#define READ_B(b, nh, bfx) do { _Pragma("unroll") for (int ni_ = 0; ni_ < 2; ++ni_) \
  _Pragma("unroll") for (int kh_ = 0; kh_ < 2; ++kh_) (bfx)[ni_ * 2 + kh_] = LDB(b, (nh) * 2 + ni_, kh_); } while (0)
#define MFMAQ(mh, nh, bfx) do { __builtin_amdgcn_s_setprio(1); \
  _Pragma("unroll") for (int mi_ = 0; mi_ < 4; ++mi_) \
  _Pragma("unroll") for (int kh_ = 0; kh_ < 2; ++kh_) \
  _Pragma("unroll") for (int ni_ = 0; ni_ < 2; ++ni_) \
    acc[(mh) * 4 + mi_][(nh) * 2 + ni_] = mfma16(af[mi_ * 2 + kh_], (bfx)[ni_ * 2 + kh_], acc[(mh) * 4 + mi_][(nh) * 2 + ni_]); \
  __builtin_amdgcn_s_setprio(0); } while (0)

DEV void gemm256_core(const short* __restrict__ A, const short* __restrict__ Bt,
                      int tileM, int tileN, short* lds, f32x4 (&acc)[8][4]) {
  const int tid = threadIdx.x;
  const int lane = tid & 63, wid = tid >> 6;
  const int wr = wid >> 2, wc = wid & 3;
  const int g = lane >> 4, r = lane & 15;

#pragma unroll
  for (int mi = 0; mi < 8; ++mi)
#pragma unroll
    for (int ni = 0; ni < 4; ++ni) acc[mi][ni] = (f32x4)0.0f;

  const short* Ag = A + (size_t)tileM * GK;
  const short* Bg = Bt + (size_t)tileN * GK;
  const int ldsA = wr * 8192;
  const int ldsB = 16384 + (wc >> 1) * 8192;
  const int brow = (wc & 1) * 64;

  auto stageA = [&](int b, int h, int kt) {
    const short* gb = Ag + (size_t)(h * 128) * GK + kt * 64;
    short* db = lds + b * 32768 + h * 8192 + (tid & 448) * 8;
#pragma unroll
    for (int i = 0; i < 2; ++i) {
      int s = i * 512 + tid;
      int row = s >> 3;
      int c = (s & 7) ^ (row & 7);
      gload16(gb + (size_t)row * GK + c * 8, db + i * 4096);
    }
  };
  auto stageB = [&](int b, int h, int kt) {
    const short* gb = Bg + (size_t)(h * 128) * GK + kt * 64;
    short* db = lds + b * 32768 + 16384 + h * 8192 + (tid & 448) * 8;
#pragma unroll
    for (int i = 0; i < 2; ++i) {
      int s = i * 512 + tid;
      int row = s >> 3;
      int c = (s & 7) ^ (row & 7);
      gload16(gb + (size_t)row * GK + c * 8, db + i * 4096);
    }
  };
  auto LDA = [&](int b, int mi, int kh) -> s16x8 {
    int row = mi * 16 + r;
    int c = (kh * 4 + g) ^ (r & 7);
    return *(const s16x8*)(lds + b * 32768 + ldsA + row * 64 + c * 8);
  };
  auto LDB = [&](int b, int ni, int kh) -> s16x8 {
    int row = brow + ni * 16 + r;
    int c = (kh * 4 + g) ^ (r & 7);
    return *(const s16x8*)(lds + b * 32768 + ldsB + row * 64 + c * 8);
  };

  s16x8 af[8], bf0[4], bf1[4];

  stageA(0, 0, 0); stageA(0, 1, 0); stageB(0, 0, 0); stageB(0, 1, 0);
  stageB(1, 0, 1); stageB(1, 1, 1);
  WAIT_VM(4);
  __builtin_amdgcn_s_barrier();

#pragma unroll 1
  for (int t = 0; t < 16; t += 2) {
    const bool s2 = (t + 2 < 16), s3 = (t + 3 < 16);
    READ_A(0, 0); READ_B(0, 0, bf0);
    stageA(1, 0, t + 1);
    bar_top(); MFMAQ(0, 0, bf0); bar_end();
    READ_B(0, 1, bf1);
    stageA(1, 1, t + 1);
    bar_top(); MFMAQ(0, 1, bf1); bar_end();
    READ_A(0, 1);
    if (s2) stageB(0, 0, t + 2);
    bar_top(); MFMAQ(1, 0, bf0); bar_end();
    if (s2) stageB(0, 1, t + 2);
    bar_top(); MFMAQ(1, 1, bf1);
    if (s2) { WAIT_VM(4); } else { WAIT_VM(0); }
    bar_end();
    READ_A(1, 0); READ_B(1, 0, bf0);
    if (s2) stageA(0, 0, t + 2);
    bar_top(); MFMAQ(0, 0, bf0); bar_end();
    READ_B(1, 1, bf1);
    if (s2) stageA(0, 1, t + 2);
    bar_top(); MFMAQ(0, 1, bf1); bar_end();
    READ_A(1, 1);
    if (s3) stageB(1, 0, t + 3);
    bar_top(); MFMAQ(1, 0, bf0); bar_end();
    if (s3) stageB(1, 1, t + 3);
    bar_top(); MFMAQ(1, 1, bf1);
    WAIT_VM(4);
    bar_end();
  }
}

// ---------------- GEMM1: qkv = x@Wqkv + b, scatter into windowed q/k/v ----------------
// q,k: [w][head][key512][d64].  v: TRANSPOSED [w][head][d64][key512] (for attn PV).
__global__ __launch_bounds__(512, 2) void k_gemm_qkv(const short* __restrict__ A, const short* __restrict__ Bt,
                                                     const float* __restrict__ bias,
                                                     short* __restrict__ qw, short* __restrict__ kw,
                                                     short* __restrict__ vw) {
  __shared__ __align__(16) short lds[65536];
  const int nwg = gridDim.x, q8 = nwg >> 3, bid = blockIdx.x;
  const int sb = (bid & 7) * q8 + (bid >> 3);
  const int bx = sb % 12, by = sb / 12;
  const int tileM = by * 256, tileN = bx * 256;
  f32x4 acc[8][4];
  gemm256_core(A, Bt, tileM, tileN, lds, acc);

  const int tid = threadIdx.x, lane = tid & 63, wid = tid >> 6;
  const int wr = wid >> 2, wc = wid & 3, g = lane >> 4, r = lane & 15;
  const int colbase = tileN + wc * 64;
  const int part = colbase >> 10;                 // wave-uniform: 0=q 1=k 2=v
  const int head = (colbase >> 6) & 15;           // wave-uniform
  if (part < 2) {
    short* buf = (part == 0) ? qw : kw;
#pragma unroll
    for (int mi = 0; mi < 8; ++mi) {
#pragma unroll
      for (int j = 0; j < 4; ++j) {
        int gr = tileM + wr * 128 + mi * 16 + g * 4 + j;
        int gx = gr >> 10, gy = (gr >> 5) & 31, gz = gr & 31;
        int w = ((gx >> 3) << 4) | ((gy >> 3) << 2) | (gz >> 3);
        int idx = ((gx & 7) << 6) | ((gy & 7) << 3) | (gz & 7);
        size_t base = ((size_t)(w * 16 + head) * 512 + idx) * 64;
#pragma unroll
        for (int ni = 0; ni < 4; ++ni) {
          int d = ni * 16 + r;
          buf[base + d] = f2bf(acc[mi][ni][j] + bias[colbase + d]);
        }
      }
    }
  } else {
#pragma unroll
    for (int mi = 0; mi < 8; ++mi) {
#pragma unroll
      for (int j = 0; j < 4; ++j) {
        int gr = tileM + wr * 128 + mi * 16 + g * 4 + j;
        int gx = gr >> 10, gy = (gr >> 5) & 31, gz = gr & 31;
        int w = ((gx >> 3) << 4) | ((gy >> 3) << 2) | (gz >> 3);
        int idx = ((gx & 7) << 6) | ((gy & 7) << 3) | (gz & 7);
        size_t base = (size_t)(w * 16 + head) * 32768 + idx;   // [d][key] major
#pragma unroll
        for (int ni = 0; ni < 4; ++ni) {
          int d = ni * 16 + r;
          vw[base + (size_t)d * 512] = f2bf(acc[mi][ni][j] + bias[colbase + d]);
        }
      }
    }
  }
}

// ---------------- GEMM2: out = h@Wout + b (fp32 out) ----------------
__global__ __launch_bounds__(512, 2) void k_gemm_out(const short* __restrict__ A, const short* __restrict__ Bt,
                                                     const float* __restrict__ bias, float* __restrict__ out) {
  __shared__ __align__(16) short lds[65536];
  const int nwg = gridDim.x, q8 = nwg >> 3, bid = blockIdx.x;
  const int sb = (bid & 7) * q8 + (bid >> 3);
  const int bx = sb & 3, by = sb >> 2;
  const int tileM = by * 256, tileN = bx * 256;
  f32x4 acc[8][4];
  gemm256_core(A, Bt, tileM, tileN, lds, acc);

  const int tid = threadIdx.x, lane = tid & 63, wid = tid >> 6;
  const int wr = wid >> 2, wc = wid & 3, g = lane >> 4, r = lane & 15;
#pragma unroll
  for (int mi = 0; mi < 8; ++mi)
#pragma unroll
    for (int j = 0; j < 4; ++j) {
      int gr = tileM + wr * 128 + mi * 16 + g * 4 + j;
#pragma unroll
      for (int ni = 0; ni < 4; ++ni) {
        int gc = tileN + wc * 64 + ni * 16 + r;
        out[(size_t)gr * C_DIM + gc] = acc[mi][ni][j] + bias[gc];
      }
    }
}

// ---------------- in-place RMS-norm + RoPE on windowed q,k ----------------
__global__ __launch_bounds__(256) void k_normrope(short* __restrict__ qw, short* __restrict__ kw,
                                                  const float* __restrict__ gq, const float* __restrict__ gk,
                                                  const float2* __restrict__ ctab) {
  const int tid = threadIdx.x, lane = tid & 63, wid = tid >> 6;
  const int g = lane >> 4, r = lane & 15;
  uint32_t rid = (uint32_t)blockIdx.x * 16 + wid * 4 + g;
  const int isK = rid >= (1u << 19);
  uint32_t rr = rid & ((1u << 19) - 1);
  short* buf = isK ? kw : qw;
  const float* gamma = isK ? gk : gq;
  uint32_t w = rr >> 13, head = (rr >> 9) & 15, idx = rr & 511;

  size_t off = (size_t)rr * 64 + r * 4;
  s16x4 v4 = *(const s16x4*)(buf + off);
  float v[4];
#pragma unroll
  for (int e = 0; e < 4; ++e) v[e] = bf2f(v4[e]);
  float ss = v[0] * v[0] + v[1] * v[1] + v[2] * v[2] + v[3] * v[3];
  ss = redsum16(ss);
  float norm = fmaxf(sqrtf(ss), 1e-12f);
  // q: fold score-scale 1/sqrt(D) AND log2(e) (attn uses exp2); k: sqrt(D)=8.
  float sc = (isK ? 8.0f : 1.4426950408889634f) / norm;
  int d0 = r * 4;
#pragma unroll
  for (int e = 0; e < 4; ++e) v[e] *= sc * gamma[head * 64 + d0 + e];

  int cx = ((w >> 4) << 3) + (idx >> 6);
  int cy = (((w >> 2) & 3) << 3) + ((idx >> 3) & 7);
  int cz = ((w & 3) << 3) + (idx & 7);
#pragma unroll
  for (int pp = 0; pp < 2; ++pp) {
    int p = r * 2 + pp;
    float c = 1.0f, s = 0.0f;
    if (p < 30) {
      int axis = (p >= 20) ? 2 : (p >= 10 ? 1 : 0);
      int fi = p - axis * 10;
      int cc = (axis == 0) ? cx : ((axis == 1) ? cy : cz);
      float2 cs = ctab[cc * 10 + fi];
      c = cs.x; s = cs.y;
    }
    float t0 = v[2 * pp], t1 = v[2 * pp + 1];
    v[2 * pp]     = t0 * c - t1 * s;
    v[2 * pp + 1] = t0 * s + t1 * c;
  }
  s16x4 o4;
#pragma unroll
  for (int e = 0; e < 4; ++e) o4[e] = f2bf(v[e]);
  *(s16x4*)(buf + off) = o4;
}

// ================ attention v3: swapped-QK, V pre-transposed in global ================
// block = (window, head, q-half): 2048 blocks x 256 threads (4 waves, 64 q each).
// K LDS [key64][d64], V^T LDS [d64][key64]; both XOR-swizzled via pre-swizzled
// gload_lds source + swizzled ds_read (identical pattern to the passing GEMM).
__global__ __launch_bounds__(256, 2) void k_attn(const short* __restrict__ qw, const short* __restrict__ kw,
                                                 const short* __restrict__ vw, short* __restrict__ hb) {
  __shared__ __align__(16) short Ks[2][4096];
  __shared__ __align__(16) short Vt[2][4096];
  __shared__ __align__(16) short Pb[4][1024];
  const int b = blockIdx.x;
  const int qh = b & 1, head = (b >> 1) & 15, w = b >> 5;
  const int tid = threadIdx.x, lane = tid & 63, wid = tid >> 6;
  const int g = lane >> 4, r = lane & 15;
  const short* Qp = qw + ((size_t)(w * 16 + head) * 512 + qh * 256 + wid * 64) * 64;
  const short* Kp = kw + (size_t)(w * 16 + head) * 32768;
  const short* Vp = vw + (size_t)(w * 16 + head) * 32768;   // [d64][key512]

  // Q-frags (B operand of swapped QK): lane (g,r) holds Q[qt*16+r][kh*32+g*8..+7]
  s16x8 qf[4][2];
#pragma unroll
  for (int qt = 0; qt < 4; ++qt)
#pragma unroll
    for (int kh = 0; kh < 2; ++kh)
      qf[qt][kh] = *(const s16x8*)(Qp + (qt * 16 + r) * 64 + kh * 32 + g * 8);

  f32x4 o[4][4];  // O^T: o[qt][nt][j] = O^T[d = nt*16+g*4+j][q = r]
#pragma unroll
  for (int qt = 0; qt < 4; ++qt)
#pragma unroll
    for (int nt = 0; nt < 4; ++nt) o[qt][nt] = (f32x4)0.f;
  float m[4] = {-1e30f, -1e30f, -1e30f, -1e30f};
  float l[4] = {0.f, 0.f, 0.f, 0.f};

  short* PwW = &Pb[wid][0];

  auto stageK = [&](int bufb, int c) {
#pragma unroll
    for (int i = 0; i < 2; ++i) {
      int ci = i * 256 + tid;
      int row = ci >> 3;                 // key 0..63
      int sc = (ci & 7) ^ (row & 7);     // pre-swizzled source col-block
      gload16(Kp + (size_t)(c * 64 + row) * 64 + sc * 8, &Ks[bufb][(i * 256 + (tid & ~63)) * 8]);
    }
  };
  auto stageV = [&](int bufb, int c) {
#pragma unroll
    for (int i = 0; i < 2; ++i) {
      int ci = i * 256 + tid;
      int row = ci >> 3;                 // d 0..63
      int sc = (ci & 7) ^ (row & 7);
      gload16(Vp + (size_t)row * 512 + c * 64 + sc * 8, &Vt[bufb][(i * 256 + (tid & ~63)) * 8]);
    }
  };

  stageK(0, 0); stageV(0, 0);

#pragma unroll 1
  for (int c = 0; c < 8; ++c) {
    const int cur = c & 1;
    if (c < 7) { stageK(cur ^ 1, c + 1); stageV(cur ^ 1, c + 1); }
    if (c < 7) { WAIT_VM(4); } else { WAIT_VM(0); }
    __builtin_amdgcn_s_barrier();

    // K-frags (A of QK^T): lane (g,r) holds K[nt*16+r][kh*32+g*8..+7]
    s16x8 kf[4][2];
#pragma unroll
    for (int nt = 0; nt < 4; ++nt)
#pragma unroll
      for (int kh = 0; kh < 2; ++kh)
        kf[nt][kh] = *(const s16x8*)(&Ks[cur][0] + (nt * 16 + r) * 64 + (((kh * 4 + g) ^ (r & 7)) << 3));
    // V^T-frags (A of PV): lane (g,r) holds V^T[nt*16+r][kh*32+g*8..+7]
    s16x8 vfr[4][2];
#pragma unroll
    for (int nt = 0; nt < 4; ++nt)
#pragma unroll
      for (int kh = 0; kh < 2; ++kh)
        vfr[nt][kh] = *(const s16x8*)(&Vt[cur][0] + (nt * 16 + r) * 64 + (((kh * 4 + g) ^ (r & 7)) << 3));

#pragma unroll
    for (int qt = 0; qt < 4; ++qt) {
      f32x4 s4[4];
#pragma unroll
      for (int nt = 0; nt < 4; ++nt) s4[nt] = (f32x4)0.f;
      __builtin_amdgcn_s_setprio(1);
#pragma unroll
      for (int nt = 0; nt < 4; ++nt)
#pragma unroll
        for (int kh = 0; kh < 2; ++kh) s4[nt] = mfma16(kf[nt][kh], qf[qt][kh], s4[nt]);
      __builtin_amdgcn_s_setprio(0);
      // in-register softmax (log2 domain): lane holds 16 of 64 scores for q=r;
      // other 48 live in lanes with same r (g varies) -> shfl_xor 16/32.
      float pm = -1e30f;
#pragma unroll
      for (int nt = 0; nt < 4; ++nt)
#pragma unroll
        for (int j = 0; j < 4; ++j) pm = fmaxf(pm, s4[nt][j]);
      pm = fmaxf(pm, __shfl_xor(pm, 16));
      pm = fmaxf(pm, __shfl_xor(pm, 32));
      float mn = fmaxf(m[qt], pm);
      float al = exp2f(m[qt] - mn);
      m[qt] = mn;
      float ps = 0.f;
#pragma unroll
      for (int nt = 0; nt < 4; ++nt)
#pragma unroll
        for (int j = 0; j < 4; ++j) { float p = exp2f(s4[nt][j] - mn); s4[nt][j] = p; ps += p; }
      ps += __shfl_xor(ps, 16);
      ps += __shfl_xor(ps, 32);
      l[qt] = l[qt] * al + ps;
#pragma unroll
      for (int nt = 0; nt < 4; ++nt) o[qt][nt] *= al;
      // P pack: P[key=nt*16+g*4+j][q=r] -> Pw[q=r][key], XOR-swizzled col-blocks
#pragma unroll
      for (int nt = 0; nt < 4; ++nt) {
        uint32_t u0 = (uint32_t)(uint16_t)f2bf(s4[nt][0]) | ((uint32_t)(uint16_t)f2bf(s4[nt][1]) << 16);
        uint32_t u1 = (uint32_t)(uint16_t)f2bf(s4[nt][2]) | ((uint32_t)(uint16_t)f2bf(s4[nt][3]) << 16);
        int col = nt * 16 + g * 4;
        int slot = (col >> 3) ^ (r & 7);
        uint2 uu; uu.x = u0; uu.y = u1;
        *(uint2*)(PwW + r * 64 + slot * 8 + (g & 1) * 4) = uu;
      }
      // B-frags of PV: P[k=kh*32+g*8+e][q=r]
      s16x8 pf0 = *(const s16x8*)(PwW + r * 64 + ((g ^ (r & 7)) << 3));
      s16x8 pf1 = *(const s16x8*)(PwW + r * 64 + (((4 + g) ^ (r & 7)) << 3));
      __builtin_amdgcn_s_setprio(1);
#pragma unroll
      for (int nt = 0; nt < 4; ++nt) {
        o[qt][nt] = mfma16(vfr[nt][0], pf0, o[qt][nt]);
        o[qt][nt] = mfma16(vfr[nt][1], pf1, o[qt][nt]);
      }
      __builtin_amdgcn_s_setprio(0);
    }
    asm volatile("s_waitcnt lgkmcnt(0)" ::: "memory");
    SB();
    __builtin_amdgcn_s_barrier();
  }

  // epilogue: O^T -> row-major bf16 h via per-wave LDS bounce
#pragma unroll
  for (int qt = 0; qt < 4; ++qt) {
    float inv = 1.f / l[qt];
#pragma unroll
    for (int nt = 0; nt < 4; ++nt) {
      uint32_t u0 = (uint32_t)(uint16_t)f2bf(o[qt][nt][0] * inv) | ((uint32_t)(uint16_t)f2bf(o[qt][nt][1] * inv) << 16);
      uint32_t u1 = (uint32_t)(uint16_t)f2bf(o[qt][nt][2] * inv) | ((uint32_t)(uint16_t)f2bf(o[qt][nt][3] * inv) << 16);
      int col = nt * 16 + g * 4;
      int slot = (col >> 3) ^ (r & 7);
      uint2 uu; uu.x = u0; uu.y = u1;
      *(uint2*)(PwW + r * 64 + slot * 8 + (g & 1) * 4) = uu;
    }
#pragma unroll
    for (int rr = 0; rr < 2; ++rr) {
      int q2 = lane >> 2;
      int cc = (lane & 3) + rr * 4;
      int slot = cc ^ (q2 & 7);
      s16x8 vv = *(const s16x8*)(PwW + q2 * 64 + slot * 8);
      int idx = qh * 256 + wid * 64 + qt * 16 + q2;
      int cx = ((w >> 4) << 3) + (idx >> 6);
      int cy = (((w >> 2) & 3) << 3) + ((idx >> 3) & 7);
      int cz = ((w & 3) << 3) + (idx & 7);
      size_t n = (size_t)cx * 1024 + cy * 32 + cz;
      *(s16x8*)(hb + n * 1024 + head * 64 + cc * 8) = vv;
    }
  }
}

extern "C" void kernel_launch(void* const* d_in, const int* in_sizes, int n_in,
                              void* d_out, int out_size, void* d_ws, size_t ws_size,
                              hipStream_t stream) {
  const float* x    = (const float*)d_in[0];
  const float* Wqkv = (const float*)d_in[2];
  const float* bqkv = (const float*)d_in[3];
  const float* gq   = (const float*)d_in[4];
  const float* gk   = (const float*)d_in[5];
  const float* Wout = (const float*)d_in[6];
  const float* bout = (const float*)d_in[7];
  float* out = (float*)d_out;

  char* ws = (char*)d_ws;
  size_t o = 0;
  auto take = [&](size_t b) { char* p = ws + o; o += (b + 255) & ~(size_t)255; return p; };
  short* xb    = (short*)take((size_t)N_TOK * C_DIM * 2);  // reused as hb after GEMM1
  short* wqkvT = (short*)take((size_t)C3 * C_DIM * 2);
  short* woutT = (short*)take((size_t)C_DIM * C_DIM * 2);
  float2* ctab = (float2*)take(320 * sizeof(float2));
  short* qw    = (short*)take((size_t)N_TOK * C_DIM * 2);
  short* kw    = (short*)take((size_t)N_TOK * C_DIM * 2);
  short* vw    = (short*)take((size_t)N_TOK * C_DIM * 2);
  short* hb = xb;

  k_cvt_x<<<(N_TOK * C_DIM) / (256 * 8), 256, 0, stream>>>(x, xb);
  k_transpose_cvt<<<dim3(C3 / 32, C_DIM / 32), 256, 0, stream>>>(Wqkv, wqkvT, C_DIM, C3);
  k_transpose_cvt<<<dim3(C_DIM / 32, C_DIM / 32), 256, 0, stream>>>(Wout, woutT, C_DIM, C_DIM);
  k_ctab<<<1, 320, 0, stream>>>(ctab);
  k_gemm_qkv<<<(C3 / 256) * (N_TOK / 256), 512, 0, stream>>>(xb, wqkvT, bqkv, qw, kw, vw);
  k_normrope<<<65536, 256, 0, stream>>>(qw, kw, gq, gk, ctab);
  k_attn<<<2048, 256, 0, stream>>>(qw, kw, vw, hb);
  k_gemm_out<<<(C_DIM / 256) * (N_TOK / 256), 512, 0, stream>>>(hb, woutT, bout, out);
}

// Round 6
// 519.946 us; speedup vs baseline: 1.3555x; 1.0745x over previous
//
#include <hip/hip_runtime.h>
#include <hip/hip_bf16.h>
#include <stdint.h>

#define DEV static __device__ __forceinline__

typedef __attribute__((ext_vector_type(4))) float f32x4;
typedef __attribute__((ext_vector_type(8))) short s16x8;
typedef __attribute__((ext_vector_type(4))) short s16x4;

constexpr int N_TOK = 32768;   // 32^3
constexpr int C_DIM = 1024;
constexpr int C3    = 3072;
constexpr int GK    = 1024;    // K for both GEMMs

DEV float bf2f(short u) { union { float f; uint32_t i; } x; x.i = ((uint32_t)(uint16_t)u) << 16; return x.f; }
DEV short f2bf(float f) { union { float f; uint32_t i; } x; x.f = f; uint32_t r = x.i + 0x7FFFu + ((x.i >> 16) & 1u); return (short)(r >> 16); }

DEV f32x4 mfma16(s16x8 a, s16x8 b, f32x4 c) {
  return __builtin_amdgcn_mfma_f32_16x16x32_bf16(a, b, c, 0, 0, 0);
}

DEV void gload16(const void* g, void* lds) {
  __builtin_amdgcn_global_load_lds((const __attribute__((address_space(1))) void*)g,
                                   (__attribute__((address_space(3))) void*)lds, 16, 0, 0);
}

#define SB() __builtin_amdgcn_sched_barrier(0)
#define WAIT_VM(N) do { asm volatile("s_waitcnt vmcnt(" #N ")" ::: "memory"); SB(); } while (0)
DEV void bar_top() { SB(); __builtin_amdgcn_s_barrier(); asm volatile("s_waitcnt lgkmcnt(0)" ::: "memory"); SB(); }
DEV void bar_end() { SB(); __builtin_amdgcn_s_barrier(); SB(); }

DEV float redsum16(float v) {
  v += __shfl_xor(v, 1); v += __shfl_xor(v, 2); v += __shfl_xor(v, 4); v += __shfl_xor(v, 8);
  return v;
}

// ---------------- fp32 -> bf16 convert (x) ----------------
__global__ void k_cvt_x(const float* __restrict__ in, short* __restrict__ outb) {
  size_t i = ((size_t)blockIdx.x * 256 + threadIdx.x) * 8;
  float4 a = *(const float4*)(in + i);
  float4 b = *(const float4*)(in + i + 4);
  s16x8 o;
  o[0] = f2bf(a.x); o[1] = f2bf(a.y); o[2] = f2bf(a.z); o[3] = f2bf(a.w);
  o[4] = f2bf(b.x); o[5] = f2bf(b.y); o[6] = f2bf(b.z); o[7] = f2bf(b.w);
  *(s16x8*)(outb + i) = o;
}

// ---------------- transpose + convert (weights -> [ncol][K] bf16) ----------------
__global__ void k_transpose_cvt(const float* __restrict__ in, short* __restrict__ outb,
                                int rin, int cin) {
  __shared__ float t[32][33];
  int tx = threadIdx.x & 31, ty = threadIdx.x >> 5;
  int c0 = blockIdx.x * 32, r0 = blockIdx.y * 32;
#pragma unroll
  for (int k = 0; k < 32; k += 8) t[ty + k][tx] = in[(size_t)(r0 + ty + k) * cin + c0 + tx];
  __syncthreads();
#pragma unroll
  for (int k = 0; k < 32; k += 8) outb[(size_t)(c0 + ty + k) * rin + r0 + tx] = f2bf(t[tx][ty + k]);
}

// ---------------- RoPE cos/sin table [32 coords][10 freqs] ----------------
__global__ void k_ctab(float2* __restrict__ ctab) {
  int t = threadIdx.x;
  if (t >= 320) return;
  int c = t / 10, fi = t % 10;
  float freq = powf(10000.0f, -(float)fi / 10.0f);
  float ph = (float)c * freq;
  ctab[t] = make_float2(cosf(ph), sinf(ph));
}

// ================= 256x256 8-phase GEMM (T2+T3+T4+T5) =================
#define READ_A(b, mh) do { _Pragma("unroll") for (int mi_ = 0; mi_ < 4; ++mi_) \
  _Pragma("unroll") for (int kh_ = 0; kh_ < 2; ++kh_) af[mi_ * 2 + kh_] = LDA(b, (mh) * 4 + mi_, kh_); } while (0)
#define READ_B(b, nh, bfx) do { _Pragma("unroll") for (int ni_ = 0; ni_ < 2; ++ni_) \
  _Pragma("unroll") for (int kh_ = 0; kh_ < 2; ++kh_) (bfx)[ni_ * 2 + kh_] = LDB(b, (nh) * 2 + ni_, kh_); } while (0)
#define MFMAQ(mh, nh, bfx) do { __builtin_amdgcn_s_setprio(1); \
  _Pragma("unroll") for (int mi_ = 0; mi_ < 4; ++mi_) \
  _Pragma("unroll") for (int kh_ = 0; kh_ < 2; ++kh_) \
  _Pragma("unroll") for (int ni_ = 0; ni_ < 2; ++ni_) \
    acc[(mh) * 4 + mi_][(nh) * 2 + ni_] = mfma16(af[mi_ * 2 + kh_], (bfx)[ni_ * 2 + kh_], acc[(mh) * 4 + mi_][(nh) * 2 + ni_]); \
  __builtin_amdgcn_s_setprio(0); } while (0)

DEV void gemm256_core(const short* __restrict__ A, const short* __restrict__ Bt,
                      int tileM, int tileN, short* lds, f32x4 (&acc)[8][4]) {
  const int tid = threadIdx.x;
  const int lane = tid & 63, wid = tid >> 6;
  const int wr = wid >> 2, wc = wid & 3;
  const int g = lane >> 4, r = lane & 15;

#pragma unroll
  for (int mi = 0; mi < 8; ++mi)
#pragma unroll
    for (int ni = 0; ni < 4; ++ni) acc[mi][ni] = (f32x4)0.0f;

  const short* Ag = A + (size_t)tileM * GK;
  const short* Bg = Bt + (size_t)tileN * GK;
  const int ldsA = wr * 8192;
  const int ldsB = 16384 + (wc >> 1) * 8192;
  const int brow = (wc & 1) * 64;

  auto stageA = [&](int b, int h, int kt) {
    const short* gb = Ag + (size_t)(h * 128) * GK + kt * 64;
    short* db = lds + b * 32768 + h * 8192 + (tid & 448) * 8;
#pragma unroll
    for (int i = 0; i < 2; ++i) {
      int s = i * 512 + tid;
      int row = s >> 3;
      int c = (s & 7) ^ (row & 7);
      gload16(gb + (size_t)row * GK + c * 8, db + i * 4096);
    }
  };
  auto stageB = [&](int b, int h, int kt) {
    const short* gb = Bg + (size_t)(h * 128) * GK + kt * 64;
    short* db = lds + b * 32768 + 16384 + h * 8192 + (tid & 448) * 8;
#pragma unroll
    for (int i = 0; i < 2; ++i) {
      int s = i * 512 + tid;
      int row = s >> 3;
      int c = (s & 7) ^ (row & 7);
      gload16(gb + (size_t)row * GK + c * 8, db + i * 4096);
    }
  };
  auto LDA = [&](int b, int mi, int kh) -> s16x8 {
    int row = mi * 16 + r;
    int c = (kh * 4 + g) ^ (r & 7);
    return *(const s16x8*)(lds + b * 32768 + ldsA + row * 64 + c * 8);
  };
  auto LDB = [&](int b, int ni, int kh) -> s16x8 {
    int row = brow + ni * 16 + r;
    int c = (kh * 4 + g) ^ (r & 7);
    return *(const s16x8*)(lds + b * 32768 + ldsB + row * 64 + c * 8);
  };

  s16x8 af[8], bf0[4], bf1[4];

  stageA(0, 0, 0); stageA(0, 1, 0); stageB(0, 0, 0); stageB(0, 1, 0);
  stageB(1, 0, 1); stageB(1, 1, 1);
  WAIT_VM(4);
  __builtin_amdgcn_s_barrier();

#pragma unroll 1
  for (int t = 0; t < 16; t += 2) {
    const bool s2 = (t + 2 < 16), s3 = (t + 3 < 16);
    READ_A(0, 0); READ_B(0, 0, bf0);
    stageA(1, 0, t + 1);
    bar_top(); MFMAQ(0, 0, bf0); bar_end();
    READ_B(0, 1, bf1);
    stageA(1, 1, t + 1);
    bar_top(); MFMAQ(0, 1, bf1); bar_end();
    READ_A(0, 1);
    if (s2) stageB(0, 0, t + 2);
    bar_top(); MFMAQ(1, 0, bf0); bar_end();
    if (s2) stageB(0, 1, t + 2);
    bar_top(); MFMAQ(1, 1, bf1);
    if (s2) { WAIT_VM(4); } else { WAIT_VM(0); }
    bar_end();
    READ_A(1, 0); READ_B(1, 0, bf0);
    if (s2) stageA(0, 0, t + 2);
    bar_top(); MFMAQ(0, 0, bf0); bar_end();
    READ_B(1, 1, bf1);
    if (s2) stageA(0, 1, t + 2);
    bar_top(); MFMAQ(0, 1, bf1); bar_end();
    READ_A(1, 1);
    if (s3) stageB(1, 0, t + 3);
    bar_top(); MFMAQ(1, 0, bf0); bar_end();
    if (s3) stageB(1, 1, t + 3);
    bar_top(); MFMAQ(1, 1, bf1);
    WAIT_VM(4);
    bar_end();
  }
}

// ---------------- GEMM1: qkv = x@Wqkv + b, fused RMS-norm+RoPE, windowed scatter ----
// q,k: [w][head][key512][d64] (normed+roped).  v: TRANSPOSED [w][head][d64][key512].
__global__ __launch_bounds__(512, 2) void k_gemm_qkv(const short* __restrict__ A, const short* __restrict__ Bt,
                                                     const float* __restrict__ bias,
                                                     const float* __restrict__ gq, const float* __restrict__ gk,
                                                     const float2* __restrict__ ctab,
                                                     short* __restrict__ qw, short* __restrict__ kw,
                                                     short* __restrict__ vw) {
  __shared__ __align__(16) short lds[65536];
  const int nwg = gridDim.x, q8 = nwg >> 3, bid = blockIdx.x;
  const int sb = (bid & 7) * q8 + (bid >> 3);
  const int bx = sb % 12, by = sb / 12;
  const int tileM = by * 256, tileN = bx * 256;
  f32x4 acc[8][4];
  gemm256_core(A, Bt, tileM, tileN, lds, acc);

  const int tid = threadIdx.x, lane = tid & 63, wid = tid >> 6;
  const int wr = wid >> 2, wc = wid & 3, g = lane >> 4, r = lane & 15;
  const int colbase = tileN + wc * 64;
  const int part = colbase >> 10;                 // block-uniform: 0=q 1=k 2=v
  const int head = (colbase >> 6) & 15;           // wave-uniform
  if (part < 2) {
    // stage ctab into now-free GEMM LDS (all waves past final barrier)
    __syncthreads();
    float2* ctl = (float2*)lds;
    if (tid < 320) ctl[tid] = ctab[tid];
    __syncthreads();
    short* buf = (part == 0) ? qw : kw;
    const float* gamma = (part == 0) ? gq : gk;
    // q: fold score-scale 1/sqrt(D) AND log2(e) (attn uses exp2); k: sqrt(D)=8.
    const float qk_sc = (part == 0) ? 1.4426950408889634f : 8.0f;
    float gam[4];
#pragma unroll
    for (int ni = 0; ni < 4; ++ni) gam[ni] = gamma[head * 64 + ni * 16 + r];
#pragma unroll
    for (int mi = 0; mi < 8; ++mi) {
#pragma unroll
      for (int j = 0; j < 4; ++j) {
        int gr = tileM + wr * 128 + mi * 16 + g * 4 + j;  // token id
        int gx = gr >> 10, gy = (gr >> 5) & 31, gz = gr & 31;
        int w = ((gx >> 3) << 4) | ((gy >> 3) << 2) | (gz >> 3);
        int idx = ((gx & 7) << 6) | ((gy & 7) << 3) | (gz & 7);
        int cx = gx, cy = gy, cz = gz;                    // grid coords = token coords
        size_t base = ((size_t)(w * 16 + head) * 512 + idx) * 64;
        float v[4];
        float ss = 0.f;
#pragma unroll
        for (int ni = 0; ni < 4; ++ni) {
          v[ni] = acc[mi][ni][j] + bias[colbase + ni * 16 + r];
          ss += v[ni] * v[ni];
        }
        ss = redsum16(ss);
        float sc = qk_sc / fmaxf(sqrtf(ss), 1e-12f);
#pragma unroll
        for (int ni = 0; ni < 4; ++ni) v[ni] *= sc * gam[ni];
#pragma unroll
        for (int ni = 0; ni < 4; ++ni) {
          int p = ni * 8 + (r >> 1);   // rotation pair index of d = ni*16+r
          float c = 1.f, s = 0.f;
          if (p < 30) {
            int axis = (p >= 20) ? 2 : (p >= 10 ? 1 : 0);
            int fi = p - axis * 10;
            int cc = (axis == 0) ? cx : ((axis == 1) ? cy : cz);
            float2 cs = ctl[cc * 10 + fi];
            c = cs.x; s = cs.y;
          }
          float vp = __shfl_xor(v[ni], 1);
          float res = (r & 1) ? (vp * s + v[ni] * c) : (v[ni] * c - vp * s);
          buf[base + ni * 16 + r] = f2bf(res);
        }
      }
    }
  } else {
#pragma unroll
    for (int mi = 0; mi < 8; ++mi) {
#pragma unroll
      for (int j = 0; j < 4; ++j) {
        int gr = tileM + wr * 128 + mi * 16 + g * 4 + j;
        int gx = gr >> 10, gy = (gr >> 5) & 31, gz = gr & 31;
        int w = ((gx >> 3) << 4) | ((gy >> 3) << 2) | (gz >> 3);
        int idx = ((gx & 7) << 6) | ((gy & 7) << 3) | (gz & 7);
        size_t base = (size_t)(w * 16 + head) * 32768 + idx;   // [d][key] major
#pragma unroll
        for (int ni = 0; ni < 4; ++ni) {
          int d = ni * 16 + r;
          vw[base + (size_t)d * 512] = f2bf(acc[mi][ni][j] + bias[colbase + d]);
        }
      }
    }
  }
}

// ---------------- GEMM2: out = h@Wout + b (fp32 out) ----------------
__global__ __launch_bounds__(512, 2) void k_gemm_out(const short* __restrict__ A, const short* __restrict__ Bt,
                                                     const float* __restrict__ bias, float* __restrict__ out) {
  __shared__ __align__(16) short lds[65536];
  const int nwg = gridDim.x, q8 = nwg >> 3, bid = blockIdx.x;
  const int sb = (bid & 7) * q8 + (bid >> 3);
  const int bx = sb & 3, by = sb >> 2;
  const int tileM = by * 256, tileN = bx * 256;
  f32x4 acc[8][4];
  gemm256_core(A, Bt, tileM, tileN, lds, acc);

  const int tid = threadIdx.x, lane = tid & 63, wid = tid >> 6;
  const int wr = wid >> 2, wc = wid & 3, g = lane >> 4, r = lane & 15;
#pragma unroll
  for (int mi = 0; mi < 8; ++mi)
#pragma unroll
    for (int j = 0; j < 4; ++j) {
      int gr = tileM + wr * 128 + mi * 16 + g * 4 + j;
#pragma unroll
      for (int ni = 0; ni < 4; ++ni) {
        int gc = tileN + wc * 64 + ni * 16 + r;
        out[(size_t)gr * C_DIM + gc] = acc[mi][ni][j] + bias[gc];
      }
    }
}

// ================ attention v3: swapped-QK, V pre-transposed in global ================
__global__ __launch_bounds__(256, 2) void k_attn(const short* __restrict__ qw, const short* __restrict__ kw,
                                                 const short* __restrict__ vw, short* __restrict__ hb) {
  __shared__ __align__(16) short Ks[2][4096];
  __shared__ __align__(16) short Vt[2][4096];
  __shared__ __align__(16) short Pb[4][1024];
  const int b = blockIdx.x;
  const int qh = b & 1, head = (b >> 1) & 15, w = b >> 5;
  const int tid = threadIdx.x, lane = tid & 63, wid = tid >> 6;
  const int g = lane >> 4, r = lane & 15;
  const short* Qp = qw + ((size_t)(w * 16 + head) * 512 + qh * 256 + wid * 64) * 64;
  const short* Kp = kw + (size_t)(w * 16 + head) * 32768;
  const short* Vp = vw + (size_t)(w * 16 + head) * 32768;   // [d64][key512]

  s16x8 qf[4][2];
#pragma unroll
  for (int qt = 0; qt < 4; ++qt)
#pragma unroll
    for (int kh = 0; kh < 2; ++kh)
      qf[qt][kh] = *(const s16x8*)(Qp + (qt * 16 + r) * 64 + kh * 32 + g * 8);

  f32x4 o[4][4];  // O^T: o[qt][nt][j] = O^T[d = nt*16+g*4+j][q = r]
#pragma unroll
  for (int qt = 0; qt < 4; ++qt)
#pragma unroll
    for (int nt = 0; nt < 4; ++nt) o[qt][nt] = (f32x4)0.f;
  float m[4] = {-1e30f, -1e30f, -1e30f, -1e30f};
  float l[4] = {0.f, 0.f, 0.f, 0.f};

  short* PwW = &Pb[wid][0];

  auto stageK = [&](int bufb, int c) {
#pragma unroll
    for (int i = 0; i < 2; ++i) {
      int ci = i * 256 + tid;
      int row = ci >> 3;
      int sc = (ci & 7) ^ (row & 7);
      gload16(Kp + (size_t)(c * 64 + row) * 64 + sc * 8, &Ks[bufb][(i * 256 + (tid & ~63)) * 8]);
    }
  };
  auto stageV = [&](int bufb, int c) {
#pragma unroll
    for (int i = 0; i < 2; ++i) {
      int ci = i * 256 + tid;
      int row = ci >> 3;
      int sc = (ci & 7) ^ (row & 7);
      gload16(Vp + (size_t)row * 512 + c * 64 + sc * 8, &Vt[bufb][(i * 256 + (tid & ~63)) * 8]);
    }
  };

  stageK(0, 0); stageV(0, 0);

#pragma unroll 1
  for (int c = 0; c < 8; ++c) {
    const int cur = c & 1;
    if (c < 7) { stageK(cur ^ 1, c + 1); stageV(cur ^ 1, c + 1); }
    if (c < 7) { WAIT_VM(4); } else { WAIT_VM(0); }
    __builtin_amdgcn_s_barrier();

    s16x8 kf[4][2];
#pragma unroll
    for (int nt = 0; nt < 4; ++nt)
#pragma unroll
      for (int kh = 0; kh < 2; ++kh)
        kf[nt][kh] = *(const s16x8*)(&Ks[cur][0] + (nt * 16 + r) * 64 + (((kh * 4 + g) ^ (r & 7)) << 3));
    s16x8 vfr[4][2];
#pragma unroll
    for (int nt = 0; nt < 4; ++nt)
#pragma unroll
      for (int kh = 0; kh < 2; ++kh)
        vfr[nt][kh] = *(const s16x8*)(&Vt[cur][0] + (nt * 16 + r) * 64 + (((kh * 4 + g) ^ (r & 7)) << 3));

#pragma unroll
    for (int qt = 0; qt < 4; ++qt) {
      f32x4 s4[4];
#pragma unroll
      for (int nt = 0; nt < 4; ++nt) s4[nt] = (f32x4)0.f;
      __builtin_amdgcn_s_setprio(1);
#pragma unroll
      for (int nt = 0; nt < 4; ++nt)
#pragma unroll
        for (int kh = 0; kh < 2; ++kh) s4[nt] = mfma16(kf[nt][kh], qf[qt][kh], s4[nt]);
      __builtin_amdgcn_s_setprio(0);
      float pm = -1e30f;
#pragma unroll
      for (int nt = 0; nt < 4; ++nt)
#pragma unroll
        for (int j = 0; j < 4; ++j) pm = fmaxf(pm, s4[nt][j]);
      pm = fmaxf(pm, __shfl_xor(pm, 16));
      pm = fmaxf(pm, __shfl_xor(pm, 32));
      float mn = fmaxf(m[qt], pm);
      float al = exp2f(m[qt] - mn);
      m[qt] = mn;
      float ps = 0.f;
#pragma unroll
      for (int nt = 0; nt < 4; ++nt)
#pragma unroll
        for (int j = 0; j < 4; ++j) { float p = exp2f(s4[nt][j] - mn); s4[nt][j] = p; ps += p; }
      ps += __shfl_xor(ps, 16);
      ps += __shfl_xor(ps, 32);
      l[qt] = l[qt] * al + ps;
#pragma unroll
      for (int nt = 0; nt < 4; ++nt) o[qt][nt] *= al;
#pragma unroll
      for (int nt = 0; nt < 4; ++nt) {
        uint32_t u0 = (uint32_t)(uint16_t)f2bf(s4[nt][0]) | ((uint32_t)(uint16_t)f2bf(s4[nt][1]) << 16);
        uint32_t u1 = (uint32_t)(uint16_t)f2bf(s4[nt][2]) | ((uint32_t)(uint16_t)f2bf(s4[nt][3]) << 16);
        int col = nt * 16 + g * 4;
        int slot = (col >> 3) ^ (r & 7);
        uint2 uu; uu.x = u0; uu.y = u1;
        *(uint2*)(PwW + r * 64 + slot * 8 + (g & 1) * 4) = uu;
      }
      s16x8 pf0 = *(const s16x8*)(PwW + r * 64 + ((g ^ (r & 7)) << 3));
      s16x8 pf1 = *(const s16x8*)(PwW + r * 64 + (((4 + g) ^ (r & 7)) << 3));
      __builtin_amdgcn_s_setprio(1);
#pragma unroll
      for (int nt = 0; nt < 4; ++nt) {
        o[qt][nt] = mfma16(vfr[nt][0], pf0, o[qt][nt]);
        o[qt][nt] = mfma16(vfr[nt][1], pf1, o[qt][nt]);
      }
      __builtin_amdgcn_s_setprio(0);
    }
    asm volatile("s_waitcnt lgkmcnt(0)" ::: "memory");
    SB();
    __builtin_amdgcn_s_barrier();
  }

#pragma unroll
  for (int qt = 0; qt < 4; ++qt) {
    float inv = 1.f / l[qt];
#pragma unroll
    for (int nt = 0; nt < 4; ++nt) {
      uint32_t u0 = (uint32_t)(uint16_t)f2bf(o[qt][nt][0] * inv) | ((uint32_t)(uint16_t)f2bf(o[qt][nt][1] * inv) << 16);
      uint32_t u1 = (uint32_t)(uint16_t)f2bf(o[qt][nt][2] * inv) | ((uint32_t)(uint16_t)f2bf(o[qt][nt][3] * inv) << 16);
      int col = nt * 16 + g * 4;
      int slot = (col >> 3) ^ (r & 7);
      uint2 uu; uu.x = u0; uu.y = u1;
      *(uint2*)(PwW + r * 64 + slot * 8 + (g & 1) * 4) = uu;
    }
#pragma unroll
    for (int rr = 0; rr < 2; ++rr) {
      int q2 = lane >> 2;
      int cc = (lane & 3) + rr * 4;
      int slot = cc ^ (q2 & 7);
      s16x8 vv = *(const s16x8*)(PwW + q2 * 64 + slot * 8);
      int idx = qh * 256 + wid * 64 + qt * 16 + q2;
      int cx = ((w >> 4) << 3) + (idx >> 6);
      int cy = (((w >> 2) & 3) << 3) + ((idx >> 3) & 7);
      int cz = ((w & 3) << 3) + (idx & 7);
      size_t n = (size_t)cx * 1024 + cy * 32 + cz;
      *(s16x8*)(hb + n * 1024 + head * 64 + cc * 8) = vv;
    }
  }
}

extern "C" void kernel_launch(void* const* d_in, const int* in_sizes, int n_in,
                              void* d_out, int out_size, void* d_ws, size_t ws_size,
                              hipStream_t stream) {
  const float* x    = (const float*)d_in[0];
  const float* Wqkv = (const float*)d_in[2];
  const float* bqkv = (const float*)d_in[3];
  const float* gq   = (const float*)d_in[4];
  const float* gk   = (const float*)d_in[5];
  const float* Wout = (const float*)d_in[6];
  const float* bout = (const float*)d_in[7];
  float* out = (float*)d_out;

  char* ws = (char*)d_ws;
  size_t o = 0;
  auto take = [&](size_t b) { char* p = ws + o; o += (b + 255) & ~(size_t)255; return p; };
  short* xb    = (short*)take((size_t)N_TOK * C_DIM * 2);  // reused as hb after GEMM1
  short* wqkvT = (short*)take((size_t)C3 * C_DIM * 2);
  short* woutT = (short*)take((size_t)C_DIM * C_DIM * 2);
  float2* ctab = (float2*)take(320 * sizeof(float2));
  short* qw    = (short*)take((size_t)N_TOK * C_DIM * 2);
  short* kw    = (short*)take((size_t)N_TOK * C_DIM * 2);
  short* vw    = (short*)take((size_t)N_TOK * C_DIM * 2);
  short* hb = xb;

  k_cvt_x<<<(N_TOK * C_DIM) / (256 * 8), 256, 0, stream>>>(x, xb);
  k_transpose_cvt<<<dim3(C3 / 32, C_DIM / 32), 256, 0, stream>>>(Wqkv, wqkvT, C_DIM, C3);
  k_transpose_cvt<<<dim3(C_DIM / 32, C_DIM / 32), 256, 0, stream>>>(Wout, woutT, C_DIM, C_DIM);
  k_ctab<<<1, 320, 0, stream>>>(ctab);
  k_gemm_qkv<<<(C3 / 256) * (N_TOK / 256), 512, 0, stream>>>(xb, wqkvT, bqkv, gq, gk, ctab, qw, kw, vw);
  k_attn<<<2048, 256, 0, stream>>>(qw, kw, vw, hb);
  k_gemm_out<<<(C_DIM / 256) * (N_TOK / 256), 512, 0, stream>>>(hb, woutT, bout, out);
}